// Round 6
// baseline (211.793 us; speedup 1.0000x reference)
//
#include <hip/hip_runtime.h>
#include <hip/hip_bf16.h>

#define SQi  2048
#define SBHi 4096            // element stride for s index: B*NH*HN
#define SCALE 0.08838834764831845f   // 1/sqrt(128)
#define PP   72              // P_lds pitch (shorts)

typedef __attribute__((ext_vector_type(4))) float f32x4;
typedef __attribute__((ext_vector_type(8))) short bf16x8;

__device__ __forceinline__ short f2bf(float f) {
    __hip_bfloat16 h = __float2bfloat16(f);
    return *reinterpret_cast<short*>(&h);
}

__device__ __forceinline__ void gld_lds16(const short* g, short* l) {
    __builtin_amdgcn_global_load_lds(
        (const __attribute__((address_space(1))) void*)g,
        (__attribute__((address_space(3))) void*)l, 16, 0, 0);
}

// ---- fused pre-pass: K,V fp32 [s][b][h][d] -> fragment-ordered bf16 ----
// KF[bh][t16][kk][lane][8]: frag(t16,kk)=16 kv x 32 d; lane(l15=kv, lhi=d-chunk)
// VF[bh][t32][nn][lane][8]: frag(t32,nn)=32 kv x 16 d; lane(l15=d,  lhi=kv-chunk)
__global__ __launch_bounds__(256)
void conv_kv(const float* __restrict__ K, const float* __restrict__ V,
             short* __restrict__ KF, short* __restrict__ VF) {
    int g = (int)blockIdx.x * 256 + (int)threadIdx.x;   // 2^21 threads
    if (g < (1 << 20)) {
        const int lane = g & 63, kk = (g >> 6) & 3, t16 = (g >> 8) & 127, bh = g >> 15;
        const int s = t16 * 16 + (lane & 15);
        const int d = kk * 32 + (lane >> 4) * 8;
        const float* in = K + (size_t)s * SBHi + (size_t)(bh >> 4) * 2048 + (bh & 15) * 128 + d;
        f32x4 a = *(const f32x4*)in;
        f32x4 b = *(const f32x4*)(in + 4);
        bf16x8 h;
        #pragma unroll
        for (int i = 0; i < 4; ++i) { h[i] = f2bf(a[i]); h[4 + i] = f2bf(b[i]); }
        *(bf16x8*)(KF + (size_t)g * 8) = h;
    } else {
        g -= (1 << 20);
        const int lane = g & 63, nn = (g >> 6) & 7, t32 = (g >> 9) & 63, bh = g >> 15;
        const int s = t32 * 32 + (lane >> 4) * 8;
        const int d = nn * 16 + (lane & 15);
        const float* in = V + (size_t)s * SBHi + (size_t)(bh >> 4) * 2048 + (bh & 15) * 128 + d;
        bf16x8 h;
        #pragma unroll
        for (int e = 0; e < 8; ++e) h[e] = f2bf(in[(size_t)e * SBHi]);
        *(bf16x8*)(VF + (size_t)g * 8) = h;
    }
}

// ---- main attention: 128-row blocks, LDS-staged KV (dbuf), 32 q-rows/wave ----
__global__ __launch_bounds__(256)
void attn_fwd6(const float* __restrict__ Q, const short* __restrict__ KF,
               const short* __restrict__ VF, float* __restrict__ O) {
    // KV[buf]: frags 0-15 = K tile (64kv x 128d), frags 16-31 = V tile. frag f at f*512+lane*8.
    __shared__ __align__(16) short KV[2][16384];
    __shared__ __align__(16) short P_lds[4][16 * PP];

    const int bid = (int)blockIdx.x;            // 512 blocks
    const int xcd = bid & 7, sl = (bid >> 3) & 31, hf = bid >> 8;
    const int bh  = xcd + 8 * (sl >> 3);        // 4 bh per XCD -> KV set ~4MB = one L2
    const int p3  = sl & 7;
    const int tile = hf ? p3 : (15 - p3);       // bids b,b+256 same CU: tiles (15-p3,p3) = 34 iters

    const size_t bh_q = (size_t)(bh >> 4) * 2048 + (size_t)(bh & 15) * 128;
    const short* KFb = KF + (size_t)bh * 262144;
    const short* VFb = VF + (size_t)bh * 262144;

    const int t = (int)threadIdx.x;
    const int lane = t & 63, wv = t >> 6, l15 = lane & 15, lhi = lane >> 4;

    const int row0w = tile * 128 + wv * 32;     // wave's 32 q-rows
    const int dtw   = (row0w + 31) >> 6;        // wave's diagonal KV tile
    const int nt    = 2 * tile + 2;             // block KV-tile count

    // Q fragments for both 16-row sets, scale folded in
    bf16x8 q0[4], q1[4];
    {
        const float* qp0 = Q + (size_t)(row0w + l15) * SBHi + bh_q + lhi * 8;
        const float* qp1 = qp0 + (size_t)16 * SBHi;
        #pragma unroll
        for (int kk = 0; kk < 4; ++kk) {
            f32x4 a = *(const f32x4*)(qp0 + kk * 32);
            f32x4 b = *(const f32x4*)(qp0 + kk * 32 + 4);
            f32x4 c = *(const f32x4*)(qp1 + kk * 32);
            f32x4 d = *(const f32x4*)(qp1 + kk * 32 + 4);
            #pragma unroll
            for (int i = 0; i < 4; ++i) {
                q0[kk][i] = f2bf(a[i] * SCALE); q0[kk][4 + i] = f2bf(b[i] * SCALE);
                q1[kk][i] = f2bf(c[i] * SCALE); q1[kk][4 + i] = f2bf(d[i] * SCALE);
            }
        }
    }

    float m0[4], l0[4], m1[4], l1[4];
    #pragma unroll
    for (int r = 0; r < 4; ++r) { m0[r] = -1e30f; l0[r] = 0.f; m1[r] = -1e30f; l1[r] = 0.f; }
    f32x4 o0[8], o1[8];
    #pragma unroll
    for (int nn = 0; nn < 8; ++nn) { o0[nn] = (f32x4){0,0,0,0}; o1[nn] = (f32x4){0,0,0,0}; }

    // staging role: wave wv stages LDS frags [8wv,8wv+8) ; wv<2 from K, wv>=2 from V
    const int fgl = (wv & 1) * 8;               // frag index within source tensor
    const int fll = wv * 8;                     // frag index within LDS
    const short* gsrc = (wv < 2) ? KFb : VFb;

    // softmax + PV for one 16-row set
    auto sm_pv = [&](f32x4 (&sa)[4], float (&mr)[4], float (&lr)[4], f32x4 (&oa)[8],
                     int rbase, bool mask, int it, const short* vb) {
        #pragma unroll
        for (int r = 0; r < 4; ++r) {
            const int rg = rbase + lhi * 4 + r;
            float s0 = sa[0][r], s1 = sa[1][r], s2 = sa[2][r], s3 = sa[3][r];
            if (mask) {
                const int c = it * 64 + l15;
                if (c      > rg) s0 = -1e30f;
                if (c + 16 > rg) s1 = -1e30f;
                if (c + 32 > rg) s2 = -1e30f;
                if (c + 48 > rg) s3 = -1e30f;
            }
            float mx = fmaxf(fmaxf(s0, s1), fmaxf(s2, s3));
            #pragma unroll
            for (int m = 1; m < 16; m <<= 1) mx = fmaxf(mx, __shfl_xor(mx, m));
            if (mx > mr[r] + 8.f) {             // defer-max (T13)
                const float corr = __expf(mr[r] - mx);
                mr[r] = mx; lr[r] *= corr;
                #pragma unroll
                for (int nn = 0; nn < 8; ++nn) oa[nn][r] *= corr;
            }
            const float mm = mr[r];
            const float p0 = __expf(s0 - mm);
            const float p1 = __expf(s1 - mm);
            const float p2 = __expf(s2 - mm);
            const float p3 = __expf(s3 - mm);
            lr[r] += (p0 + p1) + (p2 + p3);
            const int rl = (lhi * 4 + r) * PP;
            P_lds[wv][rl + l15]      = f2bf(p0);
            P_lds[wv][rl + 16 + l15] = f2bf(p1);
            P_lds[wv][rl + 32 + l15] = f2bf(p2);
            P_lds[wv][rl + 48 + l15] = f2bf(p3);
        }
        bf16x8 pa0 = *(const bf16x8*)&P_lds[wv][l15 * PP + lhi * 8];
        bf16x8 pa1 = *(const bf16x8*)&P_lds[wv][l15 * PP + 32 + lhi * 8];
        #pragma unroll
        for (int nn = 0; nn < 8; ++nn) {
            bf16x8 v0 = *(const bf16x8*)(vb + nn * 512);
            bf16x8 v1 = *(const bf16x8*)(vb + (8 + nn) * 512);
            oa[nn] = __builtin_amdgcn_mfma_f32_16x16x32_bf16(pa0, v0, oa[nn], 0, 0, 0);
            oa[nn] = __builtin_amdgcn_mfma_f32_16x16x32_bf16(pa1, v1, oa[nn], 0, 0, 0);
        }
    };

    // prologue: stage tile 0 -> buf 0
    #pragma unroll
    for (int i = 0; i < 8; ++i)
        gld_lds16(gsrc + (fgl + i) * 512 + lane * 8, &KV[0][(fll + i) * 512]);
    __syncthreads();

    for (int it = 0; it < nt; ++it) {
        const int cur = it & 1;
        if (it + 1 < nt) {                       // stage next tile (hides under compute)
            const short* gs = gsrc + (size_t)(it + 1) * 8192;
            #pragma unroll
            for (int i = 0; i < 8; ++i)
                gld_lds16(gs + (fgl + i) * 512 + lane * 8, &KV[cur ^ 1][(fll + i) * 512]);
        }
        if (it <= dtw) {                         // wave-uniform guard (tail tiles masked)
            const short* kb = &KV[cur][lane * 8];
            const short* vb = &KV[cur][8192 + lane * 8];
            // ---- S = Q K^T for both row-sets; K frag read once, used twice ----
            f32x4 sa0[4], sa1[4];
            #pragma unroll
            for (int k4 = 0; k4 < 4; ++k4) { sa0[k4] = (f32x4){0,0,0,0}; sa1[k4] = (f32x4){0,0,0,0}; }
            #pragma unroll
            for (int k4 = 0; k4 < 4; ++k4) {
                #pragma unroll
                for (int kk = 0; kk < 4; ++kk) {
                    bf16x8 kf = *(const bf16x8*)(kb + (k4 * 4 + kk) * 512);
                    sa0[k4] = __builtin_amdgcn_mfma_f32_16x16x32_bf16(q0[kk], kf, sa0[k4], 0, 0, 0);
                    sa1[k4] = __builtin_amdgcn_mfma_f32_16x16x32_bf16(q1[kk], kf, sa1[k4], 0, 0, 0);
                }
            }
            const bool mask = (it == dtw);
            sm_pv(sa0, m0, l0, o0, row0w,      mask, it, vb);
            sm_pv(sa1, m1, l1, o1, row0w + 16, mask, it, vb);
        }
        __syncthreads();
    }

    // ---- epilogue: reduce l across 16-lane groups, O / l ----
    #pragma unroll
    for (int r = 0; r < 4; ++r) {
        float ls = l0[r];
        #pragma unroll
        for (int m = 1; m < 16; m <<= 1) ls += __shfl_xor(ls, m);
        const float inv = 1.0f / ls;
        float* op = O + (size_t)(row0w + lhi * 4 + r) * SBHi + bh_q + l15;
        #pragma unroll
        for (int nn = 0; nn < 8; ++nn) op[nn * 16] = o0[nn][r] * inv;
    }
    #pragma unroll
    for (int r = 0; r < 4; ++r) {
        float ls = l1[r];
        #pragma unroll
        for (int m = 1; m < 16; m <<= 1) ls += __shfl_xor(ls, m);
        const float inv = 1.0f / ls;
        float* op = O + (size_t)(row0w + 16 + lhi * 4 + r) * SBHi + bh_q + l15;
        #pragma unroll
        for (int nn = 0; nn < 8; ++nn) op[nn * 16] = o1[nn][r] * inv;
    }
}

extern "C" void kernel_launch(void* const* d_in, const int* in_sizes, int n_in,
                              void* d_out, int out_size, void* d_ws, size_t ws_size,
                              hipStream_t stream) {
    const float* q = (const float*)d_in[0];
    const float* k = (const float*)d_in[1];
    const float* v = (const float*)d_in[2];
    float* out = (float*)d_out;

    short* KF = (short*)d_ws;                       // 16.78 MB
    short* VF = KF + (size_t)32 * 262144;           // +16.78 MB (total ~33.5 MB)

    conv_kv<<<8192, 256, 0, stream>>>(k, v, KF, VF);
    attn_fwd6<<<512, 256, 0, stream>>>(q, KF, VF, out);
}

// Round 7
// 203.711 us; speedup vs baseline: 1.0397x; 1.0397x over previous
//
#include <hip/hip_runtime.h>
#include <hip/hip_bf16.h>

#define SQi  2048
#define SBHi 4096            // element stride for s index: B*NH*HN
#define SCALE 0.08838834764831845f   // 1/sqrt(128)
#define PP   72              // P_lds pitch (shorts)

typedef __attribute__((ext_vector_type(4))) float f32x4;
typedef __attribute__((ext_vector_type(8))) short bf16x8;

__device__ __forceinline__ short f2bf(float f) {
    __hip_bfloat16 h = __float2bfloat16(f);
    return *reinterpret_cast<short*>(&h);
}

// ---- fused pre-pass: K,V fp32 [s][b][h][d] -> fragment-ordered bf16 ----
// KF[bh][t16][kk][lane][8]: frag(t16,kk)=16 kv x 32 d; lane(l15=kv, lhi=d-chunk)
// VF[bh][t32][nn][lane][8]: frag(t32,nn)=32 kv x 16 d; lane(l15=d,  lhi=kv-chunk)
__global__ __launch_bounds__(256)
void conv_kv(const float* __restrict__ K, const float* __restrict__ V,
             short* __restrict__ KF, short* __restrict__ VF) {
    int g = (int)blockIdx.x * 256 + (int)threadIdx.x;   // 2^21 threads
    if (g < (1 << 20)) {
        const int lane = g & 63, kk = (g >> 6) & 3, t16 = (g >> 8) & 127, bh = g >> 15;
        const int s = t16 * 16 + (lane & 15);
        const int d = kk * 32 + (lane >> 4) * 8;
        const float* in = K + (size_t)s * SBHi + (size_t)(bh >> 4) * 2048 + (bh & 15) * 128 + d;
        f32x4 a = *(const f32x4*)in;
        f32x4 b = *(const f32x4*)(in + 4);
        bf16x8 h;
        #pragma unroll
        for (int i = 0; i < 4; ++i) { h[i] = f2bf(a[i]); h[4 + i] = f2bf(b[i]); }
        *(bf16x8*)(KF + (size_t)g * 8) = h;
    } else {
        g -= (1 << 20);
        const int lane = g & 63, nn = (g >> 6) & 7, t32 = (g >> 9) & 63, bh = g >> 15;
        const int s = t32 * 32 + (lane >> 4) * 8;
        const int d = nn * 16 + (lane & 15);
        const float* in = V + (size_t)s * SBHi + (size_t)(bh >> 4) * 2048 + (bh & 15) * 128 + d;
        bf16x8 h;
        #pragma unroll
        for (int e = 0; e < 8; ++e) h[e] = f2bf(in[(size_t)e * SBHi]);
        *(bf16x8*)(VF + (size_t)g * 8) = h;
    }
}

// ---- main attention: barrier-free, 32 q-rows/wave (2 row-sets), shared K/V frags ----
__global__ __launch_bounds__(256)
void attn_fwd7(const float* __restrict__ Q, const short* __restrict__ KF,
               const short* __restrict__ VF, float* __restrict__ O) {
    __shared__ __align__(16) short P_lds[4][32 * PP];   // 32 rows per wave (2 sets)

    const int bid = (int)blockIdx.x;            // 512 blocks
    const int xcd = bid & 7, sl = (bid >> 3) & 31, hf = bid >> 8;
    const int bh  = xcd + 8 * (sl >> 3);        // 4 bh per XCD -> KF+VF ~4MB = one L2
    const int p3  = sl & 7;
    const int tile = hf ? p3 : (15 - p3);       // blocks b,b+256 same CU: tiles sum to 15 -> uniform

    const size_t bh_q = (size_t)(bh >> 4) * 2048 + (size_t)(bh & 15) * 128;
    const short* KFb = KF + (size_t)bh * 262144;
    const short* VFb = VF + (size_t)bh * 262144;

    const int t = (int)threadIdx.x;
    const int lane = t & 63, wv = t >> 6, l15 = lane & 15, lhi = lane >> 4;

    const int row0w = tile * 128 + wv * 32;     // wave's 32 q-rows
    const int dt    = (row0w + 31) >> 6;        // wave's diagonal KV tile (64-col units)

    // Q fragments for both 16-row sets, scale folded in
    bf16x8 q0[4], q1[4];
    {
        const float* qp0 = Q + (size_t)(row0w + l15) * SBHi + bh_q + lhi * 8;
        const float* qp1 = qp0 + (size_t)16 * SBHi;
        #pragma unroll
        for (int kk = 0; kk < 4; ++kk) {
            f32x4 a = *(const f32x4*)(qp0 + kk * 32);
            f32x4 b = *(const f32x4*)(qp0 + kk * 32 + 4);
            f32x4 c = *(const f32x4*)(qp1 + kk * 32);
            f32x4 d = *(const f32x4*)(qp1 + kk * 32 + 4);
            #pragma unroll
            for (int i = 0; i < 4; ++i) {
                q0[kk][i] = f2bf(a[i] * SCALE); q0[kk][4 + i] = f2bf(b[i] * SCALE);
                q1[kk][i] = f2bf(c[i] * SCALE); q1[kk][4 + i] = f2bf(d[i] * SCALE);
            }
        }
    }

    float m0[4], l0[4], m1[4], l1[4];
    #pragma unroll
    for (int r = 0; r < 4; ++r) { m0[r] = -1e30f; l0[r] = 0.f; m1[r] = -1e30f; l1[r] = 0.f; }
    f32x4 o0[8], o1[8];
    #pragma unroll
    for (int nn = 0; nn < 8; ++nn) { o0[nn] = (f32x4){0,0,0,0}; o1[nn] = (f32x4){0,0,0,0}; }

    // softmax for one 16-row set: s_acc -> P_lds rows [rofs, rofs+16)
    auto softmax16 = [&](f32x4 (&sa)[4], float (&mr)[4], float (&lr)[4], f32x4 (&oa)[8],
                         int rbase, int rofs, bool mask, int it) {
        #pragma unroll
        for (int r = 0; r < 4; ++r) {
            const int rg = rbase + lhi * 4 + r;
            float s0 = sa[0][r], s1 = sa[1][r], s2 = sa[2][r], s3 = sa[3][r];
            if (mask) {
                const int c = it * 64 + l15;
                if (c      > rg) s0 = -1e30f;
                if (c + 16 > rg) s1 = -1e30f;
                if (c + 32 > rg) s2 = -1e30f;
                if (c + 48 > rg) s3 = -1e30f;
            }
            float mx = fmaxf(fmaxf(s0, s1), fmaxf(s2, s3));
            #pragma unroll
            for (int m = 1; m < 16; m <<= 1) mx = fmaxf(mx, __shfl_xor(mx, m));
            if (mx > mr[r] + 8.f) {             // defer-max (T13)
                const float corr = __expf(mr[r] - mx);
                mr[r] = mx; lr[r] *= corr;
                #pragma unroll
                for (int nn = 0; nn < 8; ++nn) oa[nn][r] *= corr;
            }
            const float mm = mr[r];
            const float p0 = __expf(s0 - mm);
            const float p1 = __expf(s1 - mm);
            const float p2 = __expf(s2 - mm);
            const float p3 = __expf(s3 - mm);
            lr[r] += (p0 + p1) + (p2 + p3);
            const int rl = (rofs + lhi * 4 + r) * PP;
            P_lds[wv][rl + l15]      = f2bf(p0);
            P_lds[wv][rl + 16 + l15] = f2bf(p1);
            P_lds[wv][rl + 32 + l15] = f2bf(p2);
            P_lds[wv][rl + 48 + l15] = f2bf(p3);
        }
    };

    for (int it = 0; it <= dt; ++it) {
        // ---- S = Q K^T for both row-sets; each K fragment read once, used twice ----
        f32x4 sa0[4], sa1[4];
        #pragma unroll
        for (int k4 = 0; k4 < 4; ++k4) { sa0[k4] = (f32x4){0,0,0,0}; sa1[k4] = (f32x4){0,0,0,0}; }
        const short* kbase = KFb + (size_t)it * 8192 + lane * 8;
        #pragma unroll
        for (int k4 = 0; k4 < 4; ++k4) {
            #pragma unroll
            for (int kk = 0; kk < 4; ++kk) {
                bf16x8 kf = *(const bf16x8*)(kbase + (k4 * 4 + kk) * 512);
                sa0[k4] = __builtin_amdgcn_mfma_f32_16x16x32_bf16(q0[kk], kf, sa0[k4], 0, 0, 0);
                sa1[k4] = __builtin_amdgcn_mfma_f32_16x16x32_bf16(q1[kk], kf, sa1[k4], 0, 0, 0);
            }
        }

        // ---- first-half V fragments (kv 0-31): latency hides under softmax ----
        const short* vbase = VFb + (size_t)it * 8192 + lane * 8;
        bf16x8 vfr0[8];
        #pragma unroll
        for (int nn = 0; nn < 8; ++nn) vfr0[nn] = *(const bf16x8*)(vbase + nn * 512);

        const bool mask = (it == dt);
        softmax16(sa0, m0, l0, o0, row0w,      0,  mask, it);
        softmax16(sa1, m1, l1, o1, row0w + 16, 16, mask, it);

        // ---- P fragments for both sets ----
        bf16x8 pa00 = *(const bf16x8*)&P_lds[wv][l15 * PP + lhi * 8];          // set0, kv 0-31
        bf16x8 pa01 = *(const bf16x8*)&P_lds[wv][l15 * PP + 32 + lhi * 8];     // set0, kv 32-63
        bf16x8 pa10 = *(const bf16x8*)&P_lds[wv][(16 + l15) * PP + lhi * 8];   // set1, kv 0-31
        bf16x8 pa11 = *(const bf16x8*)&P_lds[wv][(16 + l15) * PP + 32 + lhi * 8];

        // ---- second-half V loads hide under first-half PV MFMAs ----
        bf16x8 vfr1[8];
        #pragma unroll
        for (int nn = 0; nn < 8; ++nn) vfr1[nn] = *(const bf16x8*)(vbase + (8 + nn) * 512);

        // ---- O += P V : each V fragment used by both row-sets ----
        #pragma unroll
        for (int nn = 0; nn < 8; ++nn) {
            o0[nn] = __builtin_amdgcn_mfma_f32_16x16x32_bf16(pa00, vfr0[nn], o0[nn], 0, 0, 0);
            o1[nn] = __builtin_amdgcn_mfma_f32_16x16x32_bf16(pa10, vfr0[nn], o1[nn], 0, 0, 0);
        }
        #pragma unroll
        for (int nn = 0; nn < 8; ++nn) {
            o0[nn] = __builtin_amdgcn_mfma_f32_16x16x32_bf16(pa01, vfr1[nn], o0[nn], 0, 0, 0);
            o1[nn] = __builtin_amdgcn_mfma_f32_16x16x32_bf16(pa11, vfr1[nn], o1[nn], 0, 0, 0);
        }
    }

    // ---- epilogue: reduce l across 16-lane groups, O / l ----
    #pragma unroll
    for (int r = 0; r < 4; ++r) {
        float ls = l0[r];
        #pragma unroll
        for (int m = 1; m < 16; m <<= 1) ls += __shfl_xor(ls, m);
        const float inv = 1.0f / ls;
        float* op = O + (size_t)(row0w + lhi * 4 + r) * SBHi + bh_q + l15;
        #pragma unroll
        for (int nn = 0; nn < 8; ++nn) op[nn * 16] = o0[nn][r] * inv;
    }
    #pragma unroll
    for (int r = 0; r < 4; ++r) {
        float ls = l1[r];
        #pragma unroll
        for (int m = 1; m < 16; m <<= 1) ls += __shfl_xor(ls, m);
        const float inv = 1.0f / ls;
        float* op = O + (size_t)(row0w + 16 + lhi * 4 + r) * SBHi + bh_q + l15;
        #pragma unroll
        for (int nn = 0; nn < 8; ++nn) op[nn * 16] = o1[nn][r] * inv;
    }
}

extern "C" void kernel_launch(void* const* d_in, const int* in_sizes, int n_in,
                              void* d_out, int out_size, void* d_ws, size_t ws_size,
                              hipStream_t stream) {
    const float* q = (const float*)d_in[0];
    const float* k = (const float*)d_in[1];
    const float* v = (const float*)d_in[2];
    float* out = (float*)d_out;

    short* KF = (short*)d_ws;                       // 16.78 MB
    short* VF = KF + (size_t)32 * 262144;           // +16.78 MB (total ~33.5 MB)

    conv_kv<<<8192, 256, 0, stream>>>(k, v, KF, VF);
    attn_fwd7<<<512, 256, 0, stream>>>(q, KF, VF, out);
}

// Round 8
// 140.074 us; speedup vs baseline: 1.5120x; 1.4543x over previous
//
#include <hip/hip_runtime.h>
#include <hip/hip_bf16.h>

#define SQi  2048
#define SBHi 4096            // element stride for s index: B*NH*HN
#define SCALE 0.08838834764831845f   // 1/sqrt(128)
#define PP   72              // P_lds pitch (shorts)

typedef __attribute__((ext_vector_type(4))) float f32x4;
typedef __attribute__((ext_vector_type(8))) short bf16x8;

__device__ __forceinline__ short f2bf(float f) {
    __hip_bfloat16 h = __float2bfloat16(f);
    return *reinterpret_cast<short*>(&h);
}

// ---- fused pre-pass: K,V fp32 [s][b][h][d] -> fragment-ordered bf16 ----
// KF[bh][t16][kk][lane][8]: frag(t16,kk)=16 kv x 32 d; lane(l15=kv, lhi=d-chunk)
// VF[bh][t32][nn][lane][8]: frag(t32,nn)=32 kv x 16 d; lane(l15=d,  lhi=kv-chunk)
__global__ __launch_bounds__(256)
void conv_kv(const float* __restrict__ K, const float* __restrict__ V,
             short* __restrict__ KF, short* __restrict__ VF) {
    int g = (int)blockIdx.x * 256 + (int)threadIdx.x;   // 2^21 threads
    if (g < (1 << 20)) {
        const int lane = g & 63, kk = (g >> 6) & 3, t16 = (g >> 8) & 127, bh = g >> 15;
        const int s = t16 * 16 + (lane & 15);
        const int d = kk * 32 + (lane >> 4) * 8;
        const float* in = K + (size_t)s * SBHi + (size_t)(bh >> 4) * 2048 + (bh & 15) * 128 + d;
        f32x4 a = *(const f32x4*)in;
        f32x4 b = *(const f32x4*)(in + 4);
        bf16x8 h;
        #pragma unroll
        for (int i = 0; i < 4; ++i) { h[i] = f2bf(a[i]); h[4 + i] = f2bf(b[i]); }
        *(bf16x8*)(KF + (size_t)g * 8) = h;
    } else {
        g -= (1 << 20);
        const int lane = g & 63, nn = (g >> 6) & 7, t32 = (g >> 9) & 63, bh = g >> 15;
        const int s = t32 * 32 + (lane >> 4) * 8;
        const int d = nn * 16 + (lane & 15);
        const float* in = V + (size_t)s * SBHi + (size_t)(bh >> 4) * 2048 + (bh & 15) * 128 + d;
        bf16x8 h;
        #pragma unroll
        for (int e = 0; e < 8; ++e) h[e] = f2bf(in[(size_t)e * SBHi]);
        *(bf16x8*)(VF + (size_t)g * 8) = h;
    }
}

// ---- main attention: barrier-free, 32 q-rows/wave, 8 waves/block,
//      heavy/light tiles interleaved by wave parity (uniform work per block & SIMD) ----
__global__ __launch_bounds__(512)
void attn_fwd8(const float* __restrict__ Q, const short* __restrict__ KF,
               const short* __restrict__ VF, float* __restrict__ O) {
    __shared__ __align__(16) short P_lds[8][32 * PP];   // 32 rows per wave (2 sets)

    const int bid = (int)blockIdx.x;            // 256 blocks = 8 xcd * 4 bhg * 8 p
    const int xcd = bid & 7;
    const int bhg = (bid >> 3) & 3;
    const int p   = bid >> 5;                   // 0..7
    const int bh  = xcd + 8 * bhg;              // 4 bh per XCD -> KF+VF ~4MB = one L2

    const size_t bh_q = (size_t)(bh >> 4) * 2048 + (size_t)(bh & 15) * 128;
    const short* KFb = KF + (size_t)bh * 262144;
    const short* VFb = VF + (size_t)bh * 262144;

    const int t = (int)threadIdx.x;
    const int lane = t & 63, wv = t >> 6, l15 = lane & 15, lhi = lane >> 4;

    // even waves -> heavy 128-row tile (15-p), odd waves -> light tile (p);
    // alternation balances per-SIMD work under chunked OR round-robin wave placement
    const int tile  = (wv & 1) ? p : (15 - p);
    const int row0w = tile * 128 + (wv >> 1) * 32;   // wave's 32 q-rows
    const int dt    = (row0w + 31) >> 6;             // wave's diagonal KV tile (64-col units)

    // Q fragments for both 16-row sets, scale folded in
    bf16x8 q0[4], q1[4];
    {
        const float* qp0 = Q + (size_t)(row0w + l15) * SBHi + bh_q + lhi * 8;
        const float* qp1 = qp0 + (size_t)16 * SBHi;
        #pragma unroll
        for (int kk = 0; kk < 4; ++kk) {
            f32x4 a = *(const f32x4*)(qp0 + kk * 32);
            f32x4 b = *(const f32x4*)(qp0 + kk * 32 + 4);
            f32x4 c = *(const f32x4*)(qp1 + kk * 32);
            f32x4 d = *(const f32x4*)(qp1 + kk * 32 + 4);
            #pragma unroll
            for (int i = 0; i < 4; ++i) {
                q0[kk][i] = f2bf(a[i] * SCALE); q0[kk][4 + i] = f2bf(b[i] * SCALE);
                q1[kk][i] = f2bf(c[i] * SCALE); q1[kk][4 + i] = f2bf(d[i] * SCALE);
            }
        }
    }

    float m0[4], l0[4], m1[4], l1[4];
    #pragma unroll
    for (int r = 0; r < 4; ++r) { m0[r] = -1e30f; l0[r] = 0.f; m1[r] = -1e30f; l1[r] = 0.f; }
    f32x4 o0[8], o1[8];
    #pragma unroll
    for (int nn = 0; nn < 8; ++nn) { o0[nn] = (f32x4){0,0,0,0}; o1[nn] = (f32x4){0,0,0,0}; }

    // softmax for one 16-row set: s_acc -> P_lds rows [rofs, rofs+16)
    auto softmax16 = [&](f32x4 (&sa)[4], float (&mr)[4], float (&lr)[4], f32x4 (&oa)[8],
                         int rbase, int rofs, bool mask, int it) {
        #pragma unroll
        for (int r = 0; r < 4; ++r) {
            const int rg = rbase + lhi * 4 + r;
            float s0 = sa[0][r], s1 = sa[1][r], s2 = sa[2][r], s3 = sa[3][r];
            if (mask) {
                const int c = it * 64 + l15;
                if (c      > rg) s0 = -1e30f;
                if (c + 16 > rg) s1 = -1e30f;
                if (c + 32 > rg) s2 = -1e30f;
                if (c + 48 > rg) s3 = -1e30f;
            }
            float mx = fmaxf(fmaxf(s0, s1), fmaxf(s2, s3));
            #pragma unroll
            for (int m = 1; m < 16; m <<= 1) mx = fmaxf(mx, __shfl_xor(mx, m));
            if (mx > mr[r] + 8.f) {             // defer-max (T13)
                const float corr = __expf(mr[r] - mx);
                mr[r] = mx; lr[r] *= corr;
                #pragma unroll
                for (int nn = 0; nn < 8; ++nn) oa[nn][r] *= corr;
            }
            const float mm = mr[r];
            const float p0 = __expf(s0 - mm);
            const float p1 = __expf(s1 - mm);
            const float p2 = __expf(s2 - mm);
            const float p3 = __expf(s3 - mm);
            lr[r] += (p0 + p1) + (p2 + p3);
            const int rl = (rofs + lhi * 4 + r) * PP;
            P_lds[wv][rl + l15]      = f2bf(p0);
            P_lds[wv][rl + 16 + l15] = f2bf(p1);
            P_lds[wv][rl + 32 + l15] = f2bf(p2);
            P_lds[wv][rl + 48 + l15] = f2bf(p3);
        }
    };

    for (int it = 0; it <= dt; ++it) {
        // ---- S = Q K^T for both row-sets; each K fragment read once, used twice ----
        f32x4 sa0[4], sa1[4];
        #pragma unroll
        for (int k4 = 0; k4 < 4; ++k4) { sa0[k4] = (f32x4){0,0,0,0}; sa1[k4] = (f32x4){0,0,0,0}; }
        const short* kbase = KFb + (size_t)it * 8192 + lane * 8;
        #pragma unroll
        for (int k4 = 0; k4 < 4; ++k4) {
            #pragma unroll
            for (int kk = 0; kk < 4; ++kk) {
                bf16x8 kf = *(const bf16x8*)(kbase + (k4 * 4 + kk) * 512);
                sa0[k4] = __builtin_amdgcn_mfma_f32_16x16x32_bf16(q0[kk], kf, sa0[k4], 0, 0, 0);
                sa1[k4] = __builtin_amdgcn_mfma_f32_16x16x32_bf16(q1[kk], kf, sa1[k4], 0, 0, 0);
            }
        }

        // ---- first-half V fragments (kv 0-31): latency hides under softmax ----
        const short* vbase = VFb + (size_t)it * 8192 + lane * 8;
        bf16x8 vfr0[8];
        #pragma unroll
        for (int nn = 0; nn < 8; ++nn) vfr0[nn] = *(const bf16x8*)(vbase + nn * 512);

        const bool mask = (it == dt);
        softmax16(sa0, m0, l0, o0, row0w,      0,  mask, it);
        softmax16(sa1, m1, l1, o1, row0w + 16, 16, mask, it);

        // ---- P fragments for both sets ----
        bf16x8 pa00 = *(const bf16x8*)&P_lds[wv][l15 * PP + lhi * 8];          // set0, kv 0-31
        bf16x8 pa01 = *(const bf16x8*)&P_lds[wv][l15 * PP + 32 + lhi * 8];     // set0, kv 32-63
        bf16x8 pa10 = *(const bf16x8*)&P_lds[wv][(16 + l15) * PP + lhi * 8];   // set1, kv 0-31
        bf16x8 pa11 = *(const bf16x8*)&P_lds[wv][(16 + l15) * PP + 32 + lhi * 8];

        // ---- second-half V loads hide under first-half PV MFMAs ----
        bf16x8 vfr1[8];
        #pragma unroll
        for (int nn = 0; nn < 8; ++nn) vfr1[nn] = *(const bf16x8*)(vbase + (8 + nn) * 512);

        // ---- O += P V : each V fragment used by both row-sets ----
        #pragma unroll
        for (int nn = 0; nn < 8; ++nn) {
            o0[nn] = __builtin_amdgcn_mfma_f32_16x16x32_bf16(pa00, vfr0[nn], o0[nn], 0, 0, 0);
            o1[nn] = __builtin_amdgcn_mfma_f32_16x16x32_bf16(pa10, vfr0[nn], o1[nn], 0, 0, 0);
        }
        #pragma unroll
        for (int nn = 0; nn < 8; ++nn) {
            o0[nn] = __builtin_amdgcn_mfma_f32_16x16x32_bf16(pa01, vfr1[nn], o0[nn], 0, 0, 0);
            o1[nn] = __builtin_amdgcn_mfma_f32_16x16x32_bf16(pa11, vfr1[nn], o1[nn], 0, 0, 0);
        }
    }

    // ---- epilogue: reduce l across 16-lane groups, O / l ----
    #pragma unroll
    for (int r = 0; r < 4; ++r) {
        float ls = l0[r];
        #pragma unroll
        for (int m = 1; m < 16; m <<= 1) ls += __shfl_xor(ls, m);
        const float inv = 1.0f / ls;
        float* op = O + (size_t)(row0w + lhi * 4 + r) * SBHi + bh_q + l15;
        #pragma unroll
        for (int nn = 0; nn < 8; ++nn) op[nn * 16] = o0[nn][r] * inv;
    }
    #pragma unroll
    for (int r = 0; r < 4; ++r) {
        float ls = l1[r];
        #pragma unroll
        for (int m = 1; m < 16; m <<= 1) ls += __shfl_xor(ls, m);
        const float inv = 1.0f / ls;
        float* op = O + (size_t)(row0w + 16 + lhi * 4 + r) * SBHi + bh_q + l15;
        #pragma unroll
        for (int nn = 0; nn < 8; ++nn) op[nn * 16] = o1[nn][r] * inv;
    }
}

extern "C" void kernel_launch(void* const* d_in, const int* in_sizes, int n_in,
                              void* d_out, int out_size, void* d_ws, size_t ws_size,
                              hipStream_t stream) {
    const float* q = (const float*)d_in[0];
    const float* k = (const float*)d_in[1];
    const float* v = (const float*)d_in[2];
    float* out = (float*)d_out;

    short* KF = (short*)d_ws;                       // 16.78 MB
    short* VF = KF + (size_t)32 * 262144;           // +16.78 MB (total ~33.5 MB)

    conv_kv<<<8192, 256, 0, stream>>>(k, v, KF, VF);
    attn_fwd8<<<256, 512, 0, stream>>>(q, KF, VF, out);
}